// Round 6
// baseline (2978.542 us; speedup 1.0000x reference)
//
#include <hip/hip_runtime.h>
#include <hip/hip_bf16.h>
#include <stdint.h>

static __device__ __forceinline__ ushort f2bf(float f){
  uint u = __float_as_uint(f);
  uint r = (u + 0x7fffu + ((u >> 16) & 1u)) >> 16;   // round-to-nearest-even
  return (ushort)r;
}
static __device__ __forceinline__ float bf_lo(uint v){ return __uint_as_float(v << 16); }
static __device__ __forceinline__ float bf_hi(uint v){ return __uint_as_float(v & 0xffff0000u); }

// Buckets: node range 128 per bucket (bucket = dst >> 7). NB <= 1024 (N <= 131072).

// ---------------- bucket count (LDS-aggregated histogram) ----------------

__global__ __launch_bounds__(256) void k_bcount(const int* __restrict__ dst, int E, int CH,
                                                int* __restrict__ bcnt){
  __shared__ int hist[1024];
  for (int i = threadIdx.x; i < 1024; i += 256) hist[i] = 0;
  __syncthreads();
  int begin = blockIdx.x * CH;
  int end   = min(begin + CH, E);
  int i0 = begin + threadIdx.x * 4;
  for (int i = i0; i + 4 <= end; i += 1024){
    int4 d4 = *(const int4*)&dst[i];
    atomicAdd(&hist[d4.x >> 7], 1);
    atomicAdd(&hist[d4.y >> 7], 1);
    atomicAdd(&hist[d4.z >> 7], 1);
    atomicAdd(&hist[d4.w >> 7], 1);
  }
  int tailStart = begin + ((end - begin) & ~3);
  if (tailStart < end && threadIdx.x < (end - tailStart)){
    atomicAdd(&hist[dst[tailStart + threadIdx.x] >> 7], 1);
  }
  __syncthreads();
  for (int b = threadIdx.x; b < 1024; b += 256){
    int h = hist[b];
    if (h) atomicAdd(&bcnt[b], h);
  }
}

// ---------------- bucket scan (1 wg, 1024 entries) ----------------

__global__ __launch_bounds__(256) void k_bscan(const int* __restrict__ bcnt, int* __restrict__ boff,
                                               int* __restrict__ bcur, int E){
  __shared__ int sh[256];
  int t = threadIdx.x, base = t * 4;
  int v0 = bcnt[base], v1 = bcnt[base+1], v2 = bcnt[base+2], v3 = bcnt[base+3];
  int s = v0 + v1 + v2 + v3;
  sh[t] = s; __syncthreads();
  for (int off = 1; off < 256; off <<= 1){
    int x = (t >= off) ? sh[t-off] : 0;
    __syncthreads(); sh[t] += x; __syncthreads();
  }
  int run = sh[t] - s;
  boff[base]   = run; bcur[base]   = run; run += v0;
  boff[base+1] = run; bcur[base+1] = run; run += v1;
  boff[base+2] = run; bcur[base+2] = run; run += v2;
  boff[base+3] = run; bcur[base+3] = run; run += v3;
  if (t == 255) boff[1024] = E;
}

// ---------------- bucket scatter (partition edges into ebuf, LDS reservation) ----------------

__global__ __launch_bounds__(256) void k_bscatter(const int* __restrict__ src, const int* __restrict__ dst,
                                                  int E, int CH, int* __restrict__ bcur,
                                                  uint2* __restrict__ ebuf){
  __shared__ int hist[1024];
  __shared__ int basea[1024];
  __shared__ int cnt[1024];
  for (int i = threadIdx.x; i < 1024; i += 256){ hist[i] = 0; cnt[i] = 0; }
  __syncthreads();
  int begin = blockIdx.x * CH;
  int end   = min(begin + CH, E);
  int i0 = begin + threadIdx.x * 4;
  for (int i = i0; i + 4 <= end; i += 1024){
    int4 d4 = *(const int4*)&dst[i];
    atomicAdd(&hist[d4.x >> 7], 1);
    atomicAdd(&hist[d4.y >> 7], 1);
    atomicAdd(&hist[d4.z >> 7], 1);
    atomicAdd(&hist[d4.w >> 7], 1);
  }
  int tailStart = begin + ((end - begin) & ~3);
  if (tailStart < end && threadIdx.x < (end - tailStart)){
    atomicAdd(&hist[dst[tailStart + threadIdx.x] >> 7], 1);
  }
  __syncthreads();
  for (int b = threadIdx.x; b < 1024; b += 256){
    int h = hist[b];
    basea[b] = h ? atomicAdd(&bcur[b], h) : 0;     // reserve contiguous block per bucket
  }
  __syncthreads();
  for (int i = i0; i + 4 <= end; i += 1024){
    int4 d4 = *(const int4*)&dst[i];
    int4 s4 = *(const int4*)&src[i];
    int b0 = d4.x >> 7; int p0 = basea[b0] + atomicAdd(&cnt[b0], 1); ebuf[p0] = make_uint2((uint)s4.x, (uint)d4.x);
    int b1 = d4.y >> 7; int p1 = basea[b1] + atomicAdd(&cnt[b1], 1); ebuf[p1] = make_uint2((uint)s4.y, (uint)d4.y);
    int b2 = d4.z >> 7; int p2 = basea[b2] + atomicAdd(&cnt[b2], 1); ebuf[p2] = make_uint2((uint)s4.z, (uint)d4.z);
    int b3 = d4.w >> 7; int p3 = basea[b3] + atomicAdd(&cnt[b3], 1); ebuf[p3] = make_uint2((uint)s4.w, (uint)d4.w);
  }
  if (tailStart < end && threadIdx.x < (end - tailStart)){
    int j = tailStart + threadIdx.x;
    int d = dst[j], s = src[j];
    int b = d >> 7; int p = basea[b] + atomicAdd(&cnt[b], 1); ebuf[p] = make_uint2((uint)s, (uint)d);
  }
}

// ---------------- per-bucket degree -> dinv ----------------

__global__ __launch_bounds__(256) void k_bdeg(const uint2* __restrict__ ebuf, const int* __restrict__ boff,
                                              float* __restrict__ dinv, int N){
  __shared__ int cnt[128];
  if (threadIdx.x < 128) cnt[threadIdx.x] = 0;
  __syncthreads();
  int b = blockIdx.x;
  int e0 = boff[b], e1 = boff[b+1];
  for (int i = e0 + threadIdx.x; i < e1; i += 256){
    atomicAdd(&cnt[ebuf[i].y & 127u], 1);
  }
  __syncthreads();
  int node = b * 128 + threadIdx.x;
  if (threadIdx.x < 128 && node < N) dinv[node] = rsqrtf((float)(cnt[threadIdx.x] + 1));
}

// ---------------- g = bf16((X @ W) * dinv[row])   (X:[N,128] fp32, W:[128,128]) ----------------

__global__ __launch_bounds__(256, 2) void k_gemm128(const float* __restrict__ X, const float* __restrict__ W,
                                                    const float* __restrict__ dinv, ushort* __restrict__ G, int N){
  __shared__ float Xl[128*64];   // [row][k'] current K-half, 32 KB
  __shared__ float Wl[64*128];   // [k'][col] current K-half, 32 KB
  const int tid = threadIdx.x;
  const int tx = tid & 15;       // col group: cols 8*tx .. 8*tx+7
  const int ty = tid >> 4;       // row group: rows 8*ty .. 8*ty+7
  const int r0 = blockIdx.x * 128;

  float acc[8][8];
  #pragma unroll
  for (int j=0;j<8;++j)
    #pragma unroll
    for (int c=0;c<8;++c) acc[j][c] = 0.f;

  const float2* X2 = (const float2*)X;
  const float4* W4 = (const float4*)W;
  float2* Xl2 = (float2*)Xl;
  float4* Wl4 = (float4*)Wl;

  for (int kh = 0; kh < 2; ++kh){
    if (kh) __syncthreads();
    #pragma unroll
    for (int i=0;i<16;++i){
      int t = tid + i*256;           // 0..4095
      int r = t >> 5, j = t & 31;
      int rs = r0 + r; if (rs >= N) rs = N - 1;
      Xl2[r*32 + j] = X2[(size_t)rs*64 + kh*32 + j];
    }
    #pragma unroll
    for (int i=0;i<8;++i){
      int t = tid + i*256;           // 0..2047
      int k = t >> 5, c4 = t & 31;
      Wl4[k*32 + c4] = W4[(size_t)(kh*64 + k)*32 + c4];
    }
    __syncthreads();

    #pragma unroll 4
    for (int k2 = 0; k2 < 32; ++k2){
      float2 xv[8];
      #pragma unroll
      for (int j=0;j<8;++j) xv[j] = Xl2[(8*ty + j)*32 + k2];
      float4 wa0 = Wl4[(2*k2)*32   + 2*tx];
      float4 wa1 = Wl4[(2*k2)*32   + 2*tx + 1];
      float4 wb0 = Wl4[(2*k2+1)*32 + 2*tx];
      float4 wb1 = Wl4[(2*k2+1)*32 + 2*tx + 1];
      #pragma unroll
      for (int j=0;j<8;++j){
        acc[j][0] = fmaf(xv[j].x, wa0.x, acc[j][0]);
        acc[j][1] = fmaf(xv[j].x, wa0.y, acc[j][1]);
        acc[j][2] = fmaf(xv[j].x, wa0.z, acc[j][2]);
        acc[j][3] = fmaf(xv[j].x, wa0.w, acc[j][3]);
        acc[j][4] = fmaf(xv[j].x, wa1.x, acc[j][4]);
        acc[j][5] = fmaf(xv[j].x, wa1.y, acc[j][5]);
        acc[j][6] = fmaf(xv[j].x, wa1.z, acc[j][6]);
        acc[j][7] = fmaf(xv[j].x, wa1.w, acc[j][7]);
        acc[j][0] = fmaf(xv[j].y, wb0.x, acc[j][0]);
        acc[j][1] = fmaf(xv[j].y, wb0.y, acc[j][1]);
        acc[j][2] = fmaf(xv[j].y, wb0.z, acc[j][2]);
        acc[j][3] = fmaf(xv[j].y, wb0.w, acc[j][3]);
        acc[j][4] = fmaf(xv[j].y, wb1.x, acc[j][4]);
        acc[j][5] = fmaf(xv[j].y, wb1.y, acc[j][5]);
        acc[j][6] = fmaf(xv[j].y, wb1.z, acc[j][6]);
        acc[j][7] = fmaf(xv[j].y, wb1.w, acc[j][7]);
      }
    }
  }

  #pragma unroll
  for (int j=0;j<8;++j){
    int row = r0 + 8*ty + j;
    if (row < N){
      float dv = dinv[row];
      uint p0 = (uint)f2bf(acc[j][0]*dv) | ((uint)f2bf(acc[j][1]*dv) << 16);
      uint p1 = (uint)f2bf(acc[j][2]*dv) | ((uint)f2bf(acc[j][3]*dv) << 16);
      uint p2 = (uint)f2bf(acc[j][4]*dv) | ((uint)f2bf(acc[j][5]*dv) << 16);
      uint p3 = (uint)f2bf(acc[j][6]*dv) | ((uint)f2bf(acc[j][7]*dv) << 16);
      uint4* Gp = (uint4*)&G[(size_t)row*128 + 8*tx];
      *Gp = make_uint4(p0, p1, p2, p3);
    }
  }
}

// ---------------- bucket aggregation: H[d] = relu(dinv[d]*(g[d] + sum g[src]) + b) ----------------
// One wg per 128-node bucket. 128x128 fp32 accumulator in LDS; streams unsorted bucket edges,
// gathers 256B bf16 g-rows (8-deep MLP), ds_add_f32 into dst-local row. No CSR needed.

#define AGG_ADD(dy, v) { int dl_ = (int)((dy) & 127u); \
  atomicAdd(&acc[dl_*128 + 2*lane],     bf_lo(v)); \
  atomicAdd(&acc[dl_*128 + 2*lane + 1], bf_hi(v)); }

__global__ __launch_bounds__(256, 2) void k_aggB(const ushort* __restrict__ G, const uint2* __restrict__ ebuf,
                                                 const int* __restrict__ boff, const float* __restrict__ dinv,
                                                 const float* __restrict__ bias, float* __restrict__ H, int N){
  __shared__ float acc[128*128];   // 64 KB
  __shared__ uint2 eb[256];
  const int tid = threadIdx.x;
  #pragma unroll
  for (int i=0;i<16;++i) *(float4*)&acc[(tid + i*256)*4] = make_float4(0.f,0.f,0.f,0.f);
  __syncthreads();

  const uint* Gu = (const uint*)G;   // row stride 64 uints (2 bf16 each)
  const int b  = blockIdx.x;
  const int e0 = boff[b], e1 = boff[b+1];
  const int wv   = __builtin_amdgcn_readfirstlane(tid >> 6);
  const int lane = tid & 63;

  for (int ch = e0; ch < e1; ch += 256){
    int cnt = min(256, e1 - ch);
    if (tid < cnt) eb[tid] = ebuf[ch + tid];
    __syncthreads();
    int i = wv;
    for (; i + 28 < cnt; i += 32){       // 8 edges per wave per iter (wave-stride 4)
      uint2 d0 = eb[i],    d1 = eb[i+4],  d2 = eb[i+8],  d3 = eb[i+12];
      uint2 d4 = eb[i+16], d5 = eb[i+20], d6 = eb[i+24], d7 = eb[i+28];
      uint v0 = Gu[(size_t)d0.x*64 + lane];
      uint v1 = Gu[(size_t)d1.x*64 + lane];
      uint v2 = Gu[(size_t)d2.x*64 + lane];
      uint v3 = Gu[(size_t)d3.x*64 + lane];
      uint v4 = Gu[(size_t)d4.x*64 + lane];
      uint v5 = Gu[(size_t)d5.x*64 + lane];
      uint v6 = Gu[(size_t)d6.x*64 + lane];
      uint v7 = Gu[(size_t)d7.x*64 + lane];
      AGG_ADD(d0.y, v0); AGG_ADD(d1.y, v1); AGG_ADD(d2.y, v2); AGG_ADD(d3.y, v3);
      AGG_ADD(d4.y, v4); AGG_ADD(d5.y, v5); AGG_ADD(d6.y, v6); AGG_ADD(d7.y, v7);
    }
    for (; i < cnt; i += 4){
      uint2 dd = eb[i];
      uint v = Gu[(size_t)dd.x*64 + lane];
      AGG_ADD(dd.y, v);
    }
    __syncthreads();
  }

  // epilogue: self-loop + dinv + bias + relu, fp32 out
  const int nbase = b * 128;
  for (int idx = tid; idx < 4096; idx += 256){
    int n = idx >> 5, q = idx & 31;
    int node = nbase + n;
    if (node < N){
      float4 a = *(float4*)&acc[n*128 + q*4];
      uint ua = Gu[(size_t)node*64 + 2*q];
      uint ub = Gu[(size_t)node*64 + 2*q + 1];
      float dv = dinv[node];
      float4 bb = *(const float4*)&bias[q*4];
      float4 o;
      o.x = fmaxf(fmaf(dv, a.x + bf_lo(ua), bb.x), 0.f);
      o.y = fmaxf(fmaf(dv, a.y + bf_hi(ua), bb.y), 0.f);
      o.z = fmaxf(fmaf(dv, a.z + bf_lo(ub), bb.z), 0.f);
      o.w = fmaxf(fmaf(dv, a.w + bf_hi(ub), bb.w), 0.f);
      *(float4*)&H[(size_t)node*128 + q*4] = o;
    }
  }
}

// ---------------- heads: mean = H@Wm+bm, logstd = H@Ws+bs  (H fp32, out cols = 16+16) ----------------

__global__ __launch_bounds__(256, 2) void k_heads(const float* __restrict__ H, const float* __restrict__ Wm,
                                                  const float* __restrict__ bm, const float* __restrict__ Ws,
                                                  const float* __restrict__ bs, float* __restrict__ OUT, int N){
  __shared__ float Hl[128*66];   // [row][k'] padded stride 66
  __shared__ float Wl[128*32];   // [k][col0-15=Wm,16-31=Ws]
  const int tid = threadIdx.x;
  const int tx = tid & 3;        // col group: 8*tx .. 8*tx+7
  const int ty = tid >> 2;       // rows 2*ty, 2*ty+1
  const int r0 = blockIdx.x * 128;

  for (int i = tid; i < 128*16; i += 256){
    int k = i >> 4, cc = i & 15;
    Wl[k*32 + cc]      = Wm[i];
    Wl[k*32 + 16 + cc] = Ws[i];
  }

  float acc[2][8];
  #pragma unroll
  for (int j=0;j<2;++j)
    #pragma unroll
    for (int c=0;c<8;++c) acc[j][c] = 0.f;

  const float2* H2 = (const float2*)H;
  float2* Hl2 = (float2*)Hl;     // row stride 33 float2
  const float4* Wl4 = (const float4*)Wl;

  for (int kh = 0; kh < 2; ++kh){
    if (kh) __syncthreads();
    #pragma unroll
    for (int i=0;i<16;++i){
      int t = tid + i*256;       // 0..4095
      int r = t >> 5, j = t & 31;
      int rs = r0 + r; if (rs >= N) rs = N - 1;
      Hl2[r*33 + j] = H2[(size_t)rs*64 + kh*32 + j];
    }
    __syncthreads();

    #pragma unroll 4
    for (int k2 = 0; k2 < 32; ++k2){
      float2 x0 = Hl2[(2*ty)*33 + k2];
      float2 x1 = Hl2[(2*ty+1)*33 + k2];
      float4 wa0 = Wl4[(kh*64 + 2*k2)*8   + 2*tx];
      float4 wa1 = Wl4[(kh*64 + 2*k2)*8   + 2*tx + 1];
      float4 wb0 = Wl4[(kh*64 + 2*k2+1)*8 + 2*tx];
      float4 wb1 = Wl4[(kh*64 + 2*k2+1)*8 + 2*tx + 1];
      #pragma unroll
      for (int rr=0;rr<2;++rr){
        float xa = rr ? x1.x : x0.x;
        float xb = rr ? x1.y : x0.y;
        acc[rr][0] = fmaf(xa, wa0.x, acc[rr][0]);
        acc[rr][1] = fmaf(xa, wa0.y, acc[rr][1]);
        acc[rr][2] = fmaf(xa, wa0.z, acc[rr][2]);
        acc[rr][3] = fmaf(xa, wa0.w, acc[rr][3]);
        acc[rr][4] = fmaf(xa, wa1.x, acc[rr][4]);
        acc[rr][5] = fmaf(xa, wa1.y, acc[rr][5]);
        acc[rr][6] = fmaf(xa, wa1.z, acc[rr][6]);
        acc[rr][7] = fmaf(xa, wa1.w, acc[rr][7]);
        acc[rr][0] = fmaf(xb, wb0.x, acc[rr][0]);
        acc[rr][1] = fmaf(xb, wb0.y, acc[rr][1]);
        acc[rr][2] = fmaf(xb, wb0.z, acc[rr][2]);
        acc[rr][3] = fmaf(xb, wb0.w, acc[rr][3]);
        acc[rr][4] = fmaf(xb, wb1.x, acc[rr][4]);
        acc[rr][5] = fmaf(xb, wb1.y, acc[rr][5]);
        acc[rr][6] = fmaf(xb, wb1.z, acc[rr][6]);
        acc[rr][7] = fmaf(xb, wb1.w, acc[rr][7]);
      }
    }
  }

  int c0 = 8*tx;
  float bv[8];
  #pragma unroll
  for (int i=0;i<8;++i) bv[i] = (tx < 2) ? bm[c0+i] : bs[c0+i-16];
  #pragma unroll
  for (int rr=0;rr<2;++rr){
    int row = r0 + 2*ty + rr;
    if (row < N){
      float4 o0 = make_float4(acc[rr][0]+bv[0], acc[rr][1]+bv[1], acc[rr][2]+bv[2], acc[rr][3]+bv[3]);
      float4 o1 = make_float4(acc[rr][4]+bv[4], acc[rr][5]+bv[5], acc[rr][6]+bv[6], acc[rr][7]+bv[7]);
      float* base = (tx < 2) ? &OUT[(size_t)row*16 + c0]
                             : &OUT[(size_t)N*16 + (size_t)row*16 + (c0-16)];
      float4* Op = (float4*)base;
      Op[0] = o0; Op[1] = o1;
    }
  }
}

// ---------------- host ----------------

extern "C" void kernel_launch(void* const* d_in, const int* in_sizes, int n_in,
                              void* d_out, int out_size, void* d_ws, size_t ws_size,
                              hipStream_t stream){
  const float* x  = (const float*)d_in[0];
  const int*   ei = (const int*)d_in[1];
  const float* W1 = (const float*)d_in[2];
  const float* b1 = (const float*)d_in[3];
  const float* W2 = (const float*)d_in[4];
  const float* b2 = (const float*)d_in[5];
  const float* Wm = (const float*)d_in[6];
  const float* bm = (const float*)d_in[7];
  const float* Ws = (const float*)d_in[8];
  const float* bs = (const float*)d_in[9];
  float* out = (float*)d_out;

  int N = in_sizes[0] / 128;
  int E = in_sizes[1] / 2;
  const int* src = ei;
  const int* dst = ei + E;

  char* w = (char*)d_ws;
  size_t o = 0;
  auto alloc = [&](size_t bytes)->char*{
    char* p = w + o; o = (o + bytes + 255) & ~(size_t)255; return p;
  };
  int*    bcnt = (int*)   alloc(1024*4);
  int*    boff = (int*)   alloc(1025*4);
  int*    bcur = (int*)   alloc(1024*4);
  float*  dinv = (float*) alloc((size_t)N*4);
  uint2*  ebuf = (uint2*) alloc((size_t)E*8);
  ushort* bufG = (ushort*)alloc((size_t)N*128*2);   // bf16 G (both layers)
  float*  bufH = (float*) alloc((size_t)N*128*4);   // fp32 h (both layers)
  (void)ws_size; (void)n_in; (void)out_size;

  hipMemsetAsync(bcnt, 0, 1024*4, stream);

  int NB = (N + 127)/128;            // buckets (<=1024 for this problem size)
  int CH = (E + 511)/512; CH = (CH + 3) & ~3;

  k_bcount  <<<512, 256, 0, stream>>>(dst, E, CH, bcnt);
  k_bscan   <<<1,   256, 0, stream>>>(bcnt, boff, bcur, E);
  k_bscatter<<<512, 256, 0, stream>>>(src, dst, E, CH, bcur, ebuf);
  k_bdeg    <<<NB,  256, 0, stream>>>(ebuf, boff, dinv, N);

  k_gemm128 <<<NB, 256, 0, stream>>>(x,    W1, dinv, bufG, N);               // g1 (bf16)
  k_aggB    <<<NB, 256, 0, stream>>>(bufG, ebuf, boff, dinv, b1, bufH, N);   // h1
  k_gemm128 <<<NB, 256, 0, stream>>>(bufH, W2, dinv, bufG, N);               // g2 (bf16)
  k_aggB    <<<NB, 256, 0, stream>>>(bufG, ebuf, boff, dinv, b2, bufH, N);   // h2
  k_heads   <<<NB, 256, 0, stream>>>(bufH, Wm, bm, Ws, bs, out, N);
}

// Round 10
// 404.892 us; speedup vs baseline: 7.3564x; 7.3564x over previous
//
#include <hip/hip_runtime.h>
#include <hip/hip_bf16.h>
#include <stdint.h>

static __device__ __forceinline__ ushort f2bf(float f){
  uint u = __float_as_uint(f);
  uint r = (u + 0x7fffu + ((u >> 16) & 1u)) >> 16;   // round-to-nearest-even
  return (ushort)r;
}
static __device__ __forceinline__ float bf_lo(uint v){ return __uint_as_float(v << 16); }
static __device__ __forceinline__ float bf_hi(uint v){ return __uint_as_float(v & 0xffff0000u); }

// Buckets: 128 nodes per bucket (bucket = dst >> 7). NB <= 1024 (N <= 131072).
// Edge pack: e = src | (dst&127)<<20  (requires N < 2^20; here N = 100000).

// ---------------- bucket count (LDS-aggregated histogram) ----------------

__global__ __launch_bounds__(256) void k_bcount(const int* __restrict__ dst, int E, int CH,
                                                int* __restrict__ bcnt){
  __shared__ int hist[1024];
  for (int i = threadIdx.x; i < 1024; i += 256) hist[i] = 0;
  __syncthreads();
  int begin = blockIdx.x * CH;
  int end   = min(begin + CH, E);
  int i0 = begin + threadIdx.x * 4;
  for (int i = i0; i + 4 <= end; i += 1024){
    int4 d4 = *(const int4*)&dst[i];
    atomicAdd(&hist[d4.x >> 7], 1);
    atomicAdd(&hist[d4.y >> 7], 1);
    atomicAdd(&hist[d4.z >> 7], 1);
    atomicAdd(&hist[d4.w >> 7], 1);
  }
  int tailStart = begin + ((end - begin) & ~3);
  if (tailStart < end && threadIdx.x < (end - tailStart)){
    atomicAdd(&hist[dst[tailStart + threadIdx.x] >> 7], 1);
  }
  __syncthreads();
  for (int b = threadIdx.x; b < 1024; b += 256){
    int h = hist[b];
    if (h) atomicAdd(&bcnt[b], h);
  }
}

// ---------------- bucket scan (1 wg, 1024 entries) ----------------

__global__ __launch_bounds__(256) void k_bscan(const int* __restrict__ bcnt, int* __restrict__ boff,
                                               int* __restrict__ bcur, int E){
  __shared__ int sh[256];
  int t = threadIdx.x, base = t * 4;
  int v0 = bcnt[base], v1 = bcnt[base+1], v2 = bcnt[base+2], v3 = bcnt[base+3];
  int s = v0 + v1 + v2 + v3;
  sh[t] = s; __syncthreads();
  for (int off = 1; off < 256; off <<= 1){
    int x = (t >= off) ? sh[t-off] : 0;
    __syncthreads(); sh[t] += x; __syncthreads();
  }
  int run = sh[t] - s;
  boff[base]   = run; bcur[base]   = run; run += v0;
  boff[base+1] = run; bcur[base+1] = run; run += v1;
  boff[base+2] = run; bcur[base+2] = run; run += v2;
  boff[base+3] = run; bcur[base+3] = run; run += v3;
  if (t == 255) boff[1024] = E;
}

// ---------------- bucket scatter (packed uint edges, LDS block reservation) ----------------

__global__ __launch_bounds__(256) void k_bscatter(const int* __restrict__ src, const int* __restrict__ dst,
                                                  int E, int CH, int* __restrict__ bcur,
                                                  uint* __restrict__ ebuf){
  __shared__ int hist[1024];
  __shared__ int basea[1024];
  __shared__ int cnt[1024];
  for (int i = threadIdx.x; i < 1024; i += 256){ hist[i] = 0; cnt[i] = 0; }
  __syncthreads();
  int begin = blockIdx.x * CH;
  int end   = min(begin + CH, E);
  int i0 = begin + threadIdx.x * 4;
  for (int i = i0; i + 4 <= end; i += 1024){
    int4 d4 = *(const int4*)&dst[i];
    atomicAdd(&hist[d4.x >> 7], 1);
    atomicAdd(&hist[d4.y >> 7], 1);
    atomicAdd(&hist[d4.z >> 7], 1);
    atomicAdd(&hist[d4.w >> 7], 1);
  }
  int tailStart = begin + ((end - begin) & ~3);
  if (tailStart < end && threadIdx.x < (end - tailStart)){
    atomicAdd(&hist[dst[tailStart + threadIdx.x] >> 7], 1);
  }
  __syncthreads();
  for (int b = threadIdx.x; b < 1024; b += 256){
    int h = hist[b];
    basea[b] = h ? atomicAdd(&bcur[b], h) : 0;     // reserve contiguous block per bucket
  }
  __syncthreads();
  for (int i = i0; i + 4 <= end; i += 1024){
    int4 d4 = *(const int4*)&dst[i];
    int4 s4 = *(const int4*)&src[i];
    int b0 = d4.x >> 7; int p0 = basea[b0] + atomicAdd(&cnt[b0], 1);
    ebuf[p0] = (uint)s4.x | (((uint)d4.x & 127u) << 20);
    int b1 = d4.y >> 7; int p1 = basea[b1] + atomicAdd(&cnt[b1], 1);
    ebuf[p1] = (uint)s4.y | (((uint)d4.y & 127u) << 20);
    int b2 = d4.z >> 7; int p2 = basea[b2] + atomicAdd(&cnt[b2], 1);
    ebuf[p2] = (uint)s4.z | (((uint)d4.z & 127u) << 20);
    int b3 = d4.w >> 7; int p3 = basea[b3] + atomicAdd(&cnt[b3], 1);
    ebuf[p3] = (uint)s4.w | (((uint)d4.w & 127u) << 20);
  }
  if (tailStart < end && threadIdx.x < (end - tailStart)){
    int j = tailStart + threadIdx.x;
    int d = dst[j], s = src[j];
    int b = d >> 7; int p = basea[b] + atomicAdd(&cnt[b], 1);
    ebuf[p] = (uint)s | (((uint)d & 127u) << 20);
  }
}

// ---------------- per-bucket CSR finalize: degree->dinv, node scan->ofs, scatter src->csr ----------------

__global__ __launch_bounds__(256) void k_csr(const uint* __restrict__ ebuf, const int* __restrict__ boff,
                                             float* __restrict__ dinv, int* __restrict__ ofs,
                                             int* __restrict__ csr, int N){
  __shared__ int cnt[128];
  __shared__ int esc[128];
  __shared__ int cur[128];
  const int b = blockIdx.x;
  const int t = threadIdx.x;
  if (t < 128) cnt[t] = 0;
  __syncthreads();
  const int e0 = boff[b], e1 = boff[b+1];
  for (int i = e0 + t; i < e1; i += 256){
    atomicAdd(&cnt[(ebuf[i] >> 20) & 127u], 1);
  }
  __syncthreads();
  if (t < 128) esc[t] = cnt[t];
  __syncthreads();
  for (int off = 1; off < 128; off <<= 1){
    int v = 0;
    if (t < 128 && t >= off) v = esc[t - off];
    __syncthreads();
    if (t < 128) esc[t] += v;
    __syncthreads();
  }
  if (t < 128){
    int ex = esc[t] - cnt[t];              // exclusive scan
    cur[t] = ex;
    int node = b*128 + t;
    if (node < N){
      dinv[node] = rsqrtf((float)(cnt[t] + 1));
      ofs[node]  = e0 + ex;
    } else if (node == N){
      ofs[N] = e0 + ex;                    // == e1 == E when N falls inside this bucket
    }
  }
  __syncthreads();
  for (int i = e0 + t; i < e1; i += 256){
    uint e = ebuf[i];
    int loc = (int)((e >> 20) & 127u);
    int p = e0 + atomicAdd(&cur[loc], 1);
    csr[p] = (int)(e & 0xFFFFFu);
  }
}

__global__ void k_ofs_last(int* __restrict__ ofs, int N, int E){ ofs[N] = E; }

// ---------------- g = bf16((X @ W) * dinv[row])   (X:[N,128] fp32, W:[128,128]) ----------------

__global__ __launch_bounds__(256, 2) void k_gemm128(const float* __restrict__ X, const float* __restrict__ W,
                                                    const float* __restrict__ dinv, ushort* __restrict__ G, int N){
  __shared__ float Xl[128*64];   // [row][k'] current K-half, 32 KB
  __shared__ float Wl[64*128];   // [k'][col] current K-half, 32 KB
  const int tid = threadIdx.x;
  const int tx = tid & 15;       // col group: cols 8*tx .. 8*tx+7
  const int ty = tid >> 4;       // row group: rows 8*ty .. 8*ty+7
  const int r0 = blockIdx.x * 128;

  float acc[8][8];
  #pragma unroll
  for (int j=0;j<8;++j)
    #pragma unroll
    for (int c=0;c<8;++c) acc[j][c] = 0.f;

  const float2* X2 = (const float2*)X;
  const float4* W4 = (const float4*)W;
  float2* Xl2 = (float2*)Xl;
  float4* Wl4 = (float4*)Wl;

  for (int kh = 0; kh < 2; ++kh){
    if (kh) __syncthreads();
    #pragma unroll
    for (int i=0;i<16;++i){
      int t = tid + i*256;           // 0..4095
      int r = t >> 5, j = t & 31;
      int rs = r0 + r; if (rs >= N) rs = N - 1;
      Xl2[r*32 + j] = X2[(size_t)rs*64 + kh*32 + j];
    }
    #pragma unroll
    for (int i=0;i<8;++i){
      int t = tid + i*256;           // 0..2047
      int k = t >> 5, c4 = t & 31;
      Wl4[k*32 + c4] = W4[(size_t)(kh*64 + k)*32 + c4];
    }
    __syncthreads();

    #pragma unroll 4
    for (int k2 = 0; k2 < 32; ++k2){
      float2 xv[8];
      #pragma unroll
      for (int j=0;j<8;++j) xv[j] = Xl2[(8*ty + j)*32 + k2];
      float4 wa0 = Wl4[(2*k2)*32   + 2*tx];
      float4 wa1 = Wl4[(2*k2)*32   + 2*tx + 1];
      float4 wb0 = Wl4[(2*k2+1)*32 + 2*tx];
      float4 wb1 = Wl4[(2*k2+1)*32 + 2*tx + 1];
      #pragma unroll
      for (int j=0;j<8;++j){
        acc[j][0] = fmaf(xv[j].x, wa0.x, acc[j][0]);
        acc[j][1] = fmaf(xv[j].x, wa0.y, acc[j][1]);
        acc[j][2] = fmaf(xv[j].x, wa0.z, acc[j][2]);
        acc[j][3] = fmaf(xv[j].x, wa0.w, acc[j][3]);
        acc[j][4] = fmaf(xv[j].x, wa1.x, acc[j][4]);
        acc[j][5] = fmaf(xv[j].x, wa1.y, acc[j][5]);
        acc[j][6] = fmaf(xv[j].x, wa1.z, acc[j][6]);
        acc[j][7] = fmaf(xv[j].x, wa1.w, acc[j][7]);
        acc[j][0] = fmaf(xv[j].y, wb0.x, acc[j][0]);
        acc[j][1] = fmaf(xv[j].y, wb0.y, acc[j][1]);
        acc[j][2] = fmaf(xv[j].y, wb0.z, acc[j][2]);
        acc[j][3] = fmaf(xv[j].y, wb0.w, acc[j][3]);
        acc[j][4] = fmaf(xv[j].y, wb1.x, acc[j][4]);
        acc[j][5] = fmaf(xv[j].y, wb1.y, acc[j][5]);
        acc[j][6] = fmaf(xv[j].y, wb1.z, acc[j][6]);
        acc[j][7] = fmaf(xv[j].y, wb1.w, acc[j][7]);
      }
    }
  }

  #pragma unroll
  for (int j=0;j<8;++j){
    int row = r0 + 8*ty + j;
    if (row < N){
      float dv = dinv[row];
      uint p0 = (uint)f2bf(acc[j][0]*dv) | ((uint)f2bf(acc[j][1]*dv) << 16);
      uint p1 = (uint)f2bf(acc[j][2]*dv) | ((uint)f2bf(acc[j][3]*dv) << 16);
      uint p2 = (uint)f2bf(acc[j][4]*dv) | ((uint)f2bf(acc[j][5]*dv) << 16);
      uint p3 = (uint)f2bf(acc[j][6]*dv) | ((uint)f2bf(acc[j][7]*dv) << 16);
      uint4* Gp = (uint4*)&G[(size_t)row*128 + 8*tx];
      *Gp = make_uint4(p0, p1, p2, p3);
    }
  }
}

// ---------------- out[d] = relu(dinv[d]*(g[d] + sum g[src]) + b)  (G bf16, OUT fp32) ----------------
// One wave per node; lane owns cols (2l, 2l+1) = one u32 of 2 bf16 -> 256B coalesced row gathers.

__global__ __launch_bounds__(256) void k_agg(const ushort* __restrict__ G, const int* __restrict__ ofs,
                                             const int* __restrict__ csr, const float* __restrict__ dinv,
                                             const float* __restrict__ bias, float* __restrict__ OUT, int N){
  int wv   = __builtin_amdgcn_readfirstlane((int)(threadIdx.x >> 6));
  int lane = threadIdx.x & 63;
  int d = blockIdx.x*4 + wv;
  if (d >= N) return;
  const uint* Gu = (const uint*)G;    // row stride 64 uints
  float bx = bias[2*lane], by = bias[2*lane+1];
  int e0 = ofs[d], e1 = ofs[d+1];
  uint u0 = Gu[(size_t)d*64 + lane];
  float a0x = bf_lo(u0), a0y = bf_hi(u0);
  float a1x=0.f,a1y=0.f,a2x=0.f,a2y=0.f,a3x=0.f,a3y=0.f;
  int e = e0;
  for (; e+8 <= e1; e += 8){
    int s0=csr[e],   s1=csr[e+1], s2=csr[e+2], s3=csr[e+3];
    int s4=csr[e+4], s5=csr[e+5], s6=csr[e+6], s7=csr[e+7];
    uint v0 = Gu[(size_t)s0*64 + lane];
    uint v1 = Gu[(size_t)s1*64 + lane];
    uint v2 = Gu[(size_t)s2*64 + lane];
    uint v3 = Gu[(size_t)s3*64 + lane];
    uint v4 = Gu[(size_t)s4*64 + lane];
    uint v5 = Gu[(size_t)s5*64 + lane];
    uint v6 = Gu[(size_t)s6*64 + lane];
    uint v7 = Gu[(size_t)s7*64 + lane];
    a0x += bf_lo(v0); a0y += bf_hi(v0);
    a1x += bf_lo(v1); a1y += bf_hi(v1);
    a2x += bf_lo(v2); a2y += bf_hi(v2);
    a3x += bf_lo(v3); a3y += bf_hi(v3);
    a0x += bf_lo(v4); a0y += bf_hi(v4);
    a1x += bf_lo(v5); a1y += bf_hi(v5);
    a2x += bf_lo(v6); a2y += bf_hi(v6);
    a3x += bf_lo(v7); a3y += bf_hi(v7);
  }
  for (; e+4 <= e1; e += 4){
    int s0=csr[e], s1=csr[e+1], s2=csr[e+2], s3=csr[e+3];
    uint v0 = Gu[(size_t)s0*64 + lane];
    uint v1 = Gu[(size_t)s1*64 + lane];
    uint v2 = Gu[(size_t)s2*64 + lane];
    uint v3 = Gu[(size_t)s3*64 + lane];
    a0x += bf_lo(v0); a0y += bf_hi(v0);
    a1x += bf_lo(v1); a1y += bf_hi(v1);
    a2x += bf_lo(v2); a2y += bf_hi(v2);
    a3x += bf_lo(v3); a3y += bf_hi(v3);
  }
  for (; e < e1; ++e){
    int s = csr[e];
    uint v = Gu[(size_t)s*64 + lane];
    a0x += bf_lo(v); a0y += bf_hi(v);
  }
  float sx = (a0x+a1x)+(a2x+a3x), sy = (a0y+a1y)+(a2y+a3y);
  float dv = dinv[d];
  float rx = fmaxf(fmaf(dv, sx, bx), 0.f);
  float ry = fmaxf(fmaf(dv, sy, by), 0.f);
  *(float2*)&OUT[(size_t)d*128 + 2*lane] = make_float2(rx, ry);
}

// ---------------- heads: mean = H@Wm+bm, logstd = H@Ws+bs  (H fp32, out cols = 16+16) ----------------

__global__ __launch_bounds__(256, 2) void k_heads(const float* __restrict__ H, const float* __restrict__ Wm,
                                                  const float* __restrict__ bm, const float* __restrict__ Ws,
                                                  const float* __restrict__ bs, float* __restrict__ OUT, int N){
  __shared__ float Hl[128*66];   // [row][k'] padded stride 66
  __shared__ float Wl[128*32];   // [k][col0-15=Wm,16-31=Ws]
  const int tid = threadIdx.x;
  const int tx = tid & 3;        // col group: 8*tx .. 8*tx+7
  const int ty = tid >> 2;       // rows 2*ty, 2*ty+1
  const int r0 = blockIdx.x * 128;

  for (int i = tid; i < 128*16; i += 256){
    int k = i >> 4, cc = i & 15;
    Wl[k*32 + cc]      = Wm[i];
    Wl[k*32 + 16 + cc] = Ws[i];
  }

  float acc[2][8];
  #pragma unroll
  for (int j=0;j<2;++j)
    #pragma unroll
    for (int c=0;c<8;++c) acc[j][c] = 0.f;

  const float2* H2 = (const float2*)H;
  float2* Hl2 = (float2*)Hl;     // row stride 33 float2
  const float4* Wl4 = (const float4*)Wl;

  for (int kh = 0; kh < 2; ++kh){
    if (kh) __syncthreads();
    #pragma unroll
    for (int i=0;i<16;++i){
      int t = tid + i*256;       // 0..4095
      int r = t >> 5, j = t & 31;
      int rs = r0 + r; if (rs >= N) rs = N - 1;
      Hl2[r*33 + j] = H2[(size_t)rs*64 + kh*32 + j];
    }
    __syncthreads();

    #pragma unroll 4
    for (int k2 = 0; k2 < 32; ++k2){
      float2 x0 = Hl2[(2*ty)*33 + k2];
      float2 x1 = Hl2[(2*ty+1)*33 + k2];
      float4 wa0 = Wl4[(kh*64 + 2*k2)*8   + 2*tx];
      float4 wa1 = Wl4[(kh*64 + 2*k2)*8   + 2*tx + 1];
      float4 wb0 = Wl4[(kh*64 + 2*k2+1)*8 + 2*tx];
      float4 wb1 = Wl4[(kh*64 + 2*k2+1)*8 + 2*tx + 1];
      #pragma unroll
      for (int rr=0;rr<2;++rr){
        float xa = rr ? x1.x : x0.x;
        float xb = rr ? x1.y : x0.y;
        acc[rr][0] = fmaf(xa, wa0.x, acc[rr][0]);
        acc[rr][1] = fmaf(xa, wa0.y, acc[rr][1]);
        acc[rr][2] = fmaf(xa, wa0.z, acc[rr][2]);
        acc[rr][3] = fmaf(xa, wa0.w, acc[rr][3]);
        acc[rr][4] = fmaf(xa, wa1.x, acc[rr][4]);
        acc[rr][5] = fmaf(xa, wa1.y, acc[rr][5]);
        acc[rr][6] = fmaf(xa, wa1.z, acc[rr][6]);
        acc[rr][7] = fmaf(xa, wa1.w, acc[rr][7]);
        acc[rr][0] = fmaf(xb, wb0.x, acc[rr][0]);
        acc[rr][1] = fmaf(xb, wb0.y, acc[rr][1]);
        acc[rr][2] = fmaf(xb, wb0.z, acc[rr][2]);
        acc[rr][3] = fmaf(xb, wb0.w, acc[rr][3]);
        acc[rr][4] = fmaf(xb, wb1.x, acc[rr][4]);
        acc[rr][5] = fmaf(xb, wb1.y, acc[rr][5]);
        acc[rr][6] = fmaf(xb, wb1.z, acc[rr][6]);
        acc[rr][7] = fmaf(xb, wb1.w, acc[rr][7]);
      }
    }
  }

  int c0 = 8*tx;
  float bv[8];
  #pragma unroll
  for (int i=0;i<8;++i) bv[i] = (tx < 2) ? bm[c0+i] : bs[c0+i-16];
  #pragma unroll
  for (int rr=0;rr<2;++rr){
    int row = r0 + 2*ty + rr;
    if (row < N){
      float4 o0 = make_float4(acc[rr][0]+bv[0], acc[rr][1]+bv[1], acc[rr][2]+bv[2], acc[rr][3]+bv[3]);
      float4 o1 = make_float4(acc[rr][4]+bv[4], acc[rr][5]+bv[5], acc[rr][6]+bv[6], acc[rr][7]+bv[7]);
      float* base = (tx < 2) ? &OUT[(size_t)row*16 + c0]
                             : &OUT[(size_t)N*16 + (size_t)row*16 + (c0-16)];
      float4* Op = (float4*)base;
      Op[0] = o0; Op[1] = o1;
    }
  }
}

// ---------------- host ----------------

extern "C" void kernel_launch(void* const* d_in, const int* in_sizes, int n_in,
                              void* d_out, int out_size, void* d_ws, size_t ws_size,
                              hipStream_t stream){
  const float* x  = (const float*)d_in[0];
  const int*   ei = (const int*)d_in[1];
  const float* W1 = (const float*)d_in[2];
  const float* b1 = (const float*)d_in[3];
  const float* W2 = (const float*)d_in[4];
  const float* b2 = (const float*)d_in[5];
  const float* Wm = (const float*)d_in[6];
  const float* bm = (const float*)d_in[7];
  const float* Ws = (const float*)d_in[8];
  const float* bs = (const float*)d_in[9];
  float* out = (float*)d_out;

  int N = in_sizes[0] / 128;
  int E = in_sizes[1] / 2;
  const int* src = ei;
  const int* dst = ei + E;

  char* w = (char*)d_ws;
  size_t o = 0;
  auto alloc = [&](size_t bytes)->char*{
    char* p = w + o; o = (o + bytes + 255) & ~(size_t)255; return p;
  };
  int*    bcnt = (int*)   alloc(1024*4);
  int*    boff = (int*)   alloc(1025*4);
  int*    bcur = (int*)   alloc(1024*4);
  float*  dinv = (float*) alloc((size_t)N*4);
  int*    ofs  = (int*)   alloc((size_t)(N+1)*4);
  uint*   ebuf = (uint*)  alloc((size_t)E*4);
  int*    csr  = (int*)   alloc((size_t)E*4);
  ushort* bufG = (ushort*)alloc((size_t)N*128*2);   // bf16 G (both layers)
  float*  bufH = (float*) alloc((size_t)N*128*4);   // fp32 h (both layers)
  (void)ws_size; (void)n_in; (void)out_size;

  hipMemsetAsync(bcnt, 0, 1024*4, stream);

  int NB = (N + 127)/128;                     // 782 buckets for N=100000
  int CH = (E + 255)/256; CH = (CH + 3) & ~3; // chunk per wg for 256-wg passes

  k_bcount  <<<256, 256, 0, stream>>>(dst, E, CH, bcnt);
  k_bscan   <<<1,   256, 0, stream>>>(bcnt, boff, bcur, E);
  k_bscatter<<<256, 256, 0, stream>>>(src, dst, E, CH, bcur, ebuf);
  k_csr     <<<NB,  256, 0, stream>>>(ebuf, boff, dinv, ofs, csr, N);
  if ((N & 127) == 0) k_ofs_last<<<1, 1, 0, stream>>>(ofs, N, E);  // only when N%128==0 (not hit for 100000)

  int gAgg = (N + 3)/4;

  k_gemm128<<<NB,   256, 0, stream>>>(x,    W1, dinv, bufG, N);             // g1 (bf16)
  k_agg    <<<gAgg, 256, 0, stream>>>(bufG, ofs, csr, dinv, b1, bufH, N);   // h1 = relu(...) fp32
  k_gemm128<<<NB,   256, 0, stream>>>(bufH, W2, dinv, bufG, N);             // g2 (bf16)
  k_agg    <<<gAgg, 256, 0, stream>>>(bufG, ofs, csr, dinv, b2, bufH, N);   // h2 fp32
  k_heads  <<<NB,   256, 0, stream>>>(bufH, Wm, bm, Ws, bs, out, N);
}

// Round 11
// 335.927 us; speedup vs baseline: 8.8666x; 1.2053x over previous
//
#include <hip/hip_runtime.h>
#include <hip/hip_bf16.h>
#include <stdint.h>

static __device__ __forceinline__ ushort f2bf(float f){
  uint u = __float_as_uint(f);
  uint r = (u + 0x7fffu + ((u >> 16) & 1u)) >> 16;   // round-to-nearest-even
  return (ushort)r;
}
static __device__ __forceinline__ float bf_lo(uint v){ return __uint_as_float(v << 16); }
static __device__ __forceinline__ float bf_hi(uint v){ return __uint_as_float(v & 0xffff0000u); }

using short8 = __attribute__((ext_vector_type(8))) short;
using f32x4  = __attribute__((ext_vector_type(4))) float;

// Buckets: 128 nodes per bucket (bucket = dst >> 7). NB <= 1024 (N <= 131072).
// Edge pack: e = src | (dst&127)<<20  (requires N < 2^20; here N = 100000).

// ---------------- bucket count (LDS-aggregated histogram) ----------------

__global__ __launch_bounds__(256) void k_bcount(const int* __restrict__ dst, int E, int CH,
                                                int* __restrict__ bcnt){
  __shared__ int hist[1024];
  for (int i = threadIdx.x; i < 1024; i += 256) hist[i] = 0;
  __syncthreads();
  int begin = blockIdx.x * CH;
  int end   = min(begin + CH, E);
  int i0 = begin + threadIdx.x * 4;
  for (int i = i0; i + 4 <= end; i += 1024){
    int4 d4 = *(const int4*)&dst[i];
    atomicAdd(&hist[d4.x >> 7], 1);
    atomicAdd(&hist[d4.y >> 7], 1);
    atomicAdd(&hist[d4.z >> 7], 1);
    atomicAdd(&hist[d4.w >> 7], 1);
  }
  int tailStart = begin + ((end - begin) & ~3);
  if (tailStart < end && threadIdx.x < (end - tailStart)){
    atomicAdd(&hist[dst[tailStart + threadIdx.x] >> 7], 1);
  }
  __syncthreads();
  for (int b = threadIdx.x; b < 1024; b += 256){
    int h = hist[b];
    if (h) atomicAdd(&bcnt[b], h);
  }
}

// ---------------- bucket scan (1 wg, 1024 entries) ----------------

__global__ __launch_bounds__(256) void k_bscan(const int* __restrict__ bcnt, int* __restrict__ boff,
                                               int* __restrict__ bcur, int E){
  __shared__ int sh[256];
  int t = threadIdx.x, base = t * 4;
  int v0 = bcnt[base], v1 = bcnt[base+1], v2 = bcnt[base+2], v3 = bcnt[base+3];
  int s = v0 + v1 + v2 + v3;
  sh[t] = s; __syncthreads();
  for (int off = 1; off < 256; off <<= 1){
    int x = (t >= off) ? sh[t-off] : 0;
    __syncthreads(); sh[t] += x; __syncthreads();
  }
  int run = sh[t] - s;
  boff[base]   = run; bcur[base]   = run; run += v0;
  boff[base+1] = run; bcur[base+1] = run; run += v1;
  boff[base+2] = run; bcur[base+2] = run; run += v2;
  boff[base+3] = run; bcur[base+3] = run; run += v3;
  if (t == 255) boff[1024] = E;
}

// ---------------- bucket scatter (packed uint edges, LDS block reservation) ----------------

__global__ __launch_bounds__(256) void k_bscatter(const int* __restrict__ src, const int* __restrict__ dst,
                                                  int E, int CH, int* __restrict__ bcur,
                                                  uint* __restrict__ ebuf){
  __shared__ int hist[1024];
  __shared__ int basea[1024];
  __shared__ int cnt[1024];
  for (int i = threadIdx.x; i < 1024; i += 256){ hist[i] = 0; cnt[i] = 0; }
  __syncthreads();
  int begin = blockIdx.x * CH;
  int end   = min(begin + CH, E);
  int i0 = begin + threadIdx.x * 4;
  for (int i = i0; i + 4 <= end; i += 1024){
    int4 d4 = *(const int4*)&dst[i];
    atomicAdd(&hist[d4.x >> 7], 1);
    atomicAdd(&hist[d4.y >> 7], 1);
    atomicAdd(&hist[d4.z >> 7], 1);
    atomicAdd(&hist[d4.w >> 7], 1);
  }
  int tailStart = begin + ((end - begin) & ~3);
  if (tailStart < end && threadIdx.x < (end - tailStart)){
    atomicAdd(&hist[dst[tailStart + threadIdx.x] >> 7], 1);
  }
  __syncthreads();
  for (int b = threadIdx.x; b < 1024; b += 256){
    int h = hist[b];
    basea[b] = h ? atomicAdd(&bcur[b], h) : 0;     // reserve contiguous block per bucket
  }
  __syncthreads();
  for (int i = i0; i + 4 <= end; i += 1024){
    int4 d4 = *(const int4*)&dst[i];
    int4 s4 = *(const int4*)&src[i];
    int b0 = d4.x >> 7; int p0 = basea[b0] + atomicAdd(&cnt[b0], 1);
    ebuf[p0] = (uint)s4.x | (((uint)d4.x & 127u) << 20);
    int b1 = d4.y >> 7; int p1 = basea[b1] + atomicAdd(&cnt[b1], 1);
    ebuf[p1] = (uint)s4.y | (((uint)d4.y & 127u) << 20);
    int b2 = d4.z >> 7; int p2 = basea[b2] + atomicAdd(&cnt[b2], 1);
    ebuf[p2] = (uint)s4.z | (((uint)d4.z & 127u) << 20);
    int b3 = d4.w >> 7; int p3 = basea[b3] + atomicAdd(&cnt[b3], 1);
    ebuf[p3] = (uint)s4.w | (((uint)d4.w & 127u) << 20);
  }
  if (tailStart < end && threadIdx.x < (end - tailStart)){
    int j = tailStart + threadIdx.x;
    int d = dst[j], s = src[j];
    int b = d >> 7; int p = basea[b] + atomicAdd(&cnt[b], 1);
    ebuf[p] = (uint)s | (((uint)d & 127u) << 20);
  }
}

// ---------------- per-bucket CSR finalize: degree->dinv, node scan->ofs, scatter src->csr ----------------

__global__ __launch_bounds__(256) void k_csr(const uint* __restrict__ ebuf, const int* __restrict__ boff,
                                             float* __restrict__ dinv, int* __restrict__ ofs,
                                             int* __restrict__ csr, int N){
  __shared__ int cnt[128];
  __shared__ int esc[128];
  __shared__ int cur[128];
  const int b = blockIdx.x;
  const int t = threadIdx.x;
  if (t < 128) cnt[t] = 0;
  __syncthreads();
  const int e0 = boff[b], e1 = boff[b+1];
  for (int i = e0 + t; i < e1; i += 256){
    atomicAdd(&cnt[(ebuf[i] >> 20) & 127u], 1);
  }
  __syncthreads();
  if (t < 128) esc[t] = cnt[t];
  __syncthreads();
  for (int off = 1; off < 128; off <<= 1){
    int v = 0;
    if (t < 128 && t >= off) v = esc[t - off];
    __syncthreads();
    if (t < 128) esc[t] += v;
    __syncthreads();
  }
  if (t < 128){
    int ex = esc[t] - cnt[t];              // exclusive scan
    cur[t] = ex;
    int node = b*128 + t;
    if (node < N){
      dinv[node] = rsqrtf((float)(cnt[t] + 1));
      ofs[node]  = e0 + ex;
    } else if (node == N){
      ofs[N] = e0 + ex;                    // == e1 == E when N falls inside this bucket
    }
  }
  __syncthreads();
  for (int i = e0 + t; i < e1; i += 256){
    uint e = ebuf[i];
    int loc = (int)((e >> 20) & 127u);
    int p = e0 + atomicAdd(&cur[loc], 1);
    csr[p] = (int)(e & 0xFFFFFu);
  }
}

__global__ void k_ofs_last(int* __restrict__ ofs, int N, int E){ ofs[N] = E; }

// ---------------- g = bf16((X @ W) * dinv[row])  via MFMA bf16 (X fp32 -> bf16 staged) ----------------
// Tile 128x128, whole K=128 in LDS (Xl + Wt = 64 KB). XOR-swizzled layout:
//   elem (r, k) at r*128 + 8*((k/8) ^ (r&7)) + (k&7)   -> all frag reads / staged writes bank-conflict-free.
// 4 waves; wave w owns rows 32w..32w+31 (2 tiles of 16) x 8 col tiles; 64 MFMAs/wave.
// Fragment layouts (gfx950 16x16x32): A row=lane&15, k=8*(lane>>4)+i; B col=lane&15, same k;
// C/D col=lane&15, row=4*(lane>>4)+reg  [verified mapping, guide S3].

__global__ __launch_bounds__(256, 2) void k_gemm_mfma(const float* __restrict__ X, const float* __restrict__ W,
                                                      const float* __restrict__ dinv, ushort* __restrict__ G, int N){
  __shared__ ushort Xl[128*128];   // 32 KB  [row][k] swizzled
  __shared__ ushort Wt[128*128];   // 32 KB  [col][k] swizzled (W transposed)
  const int tid = threadIdx.x;
  const int r0 = blockIdx.x * 128;

  // stage X -> bf16, swizzled
  #pragma unroll
  for (int i = 0; i < 16; ++i){
    int t = tid + i*256;             // 0..4095
    int row = t >> 5, f4 = t & 31;   // f4: which float4 of the row
    int rs = r0 + row; if (rs >= N) rs = N - 1;
    float4 v = *(const float4*)&X[(size_t)rs*128 + f4*4];
    uint p0 = (uint)f2bf(v.x) | ((uint)f2bf(v.y) << 16);
    uint p1 = (uint)f2bf(v.z) | ((uint)f2bf(v.w) << 16);
    int kb = f4 >> 1, sub = (f4 & 1) * 4;
    *(uint2*)&Xl[row*128 + ((kb ^ (row & 7)) << 3) + sub] = make_uint2(p0, p1);
  }
  // stage W^T -> bf16, swizzled (per-j reads are coalesced rows of W; W is L2-resident)
  #pragma unroll
  for (int i = 0; i < 8; ++i){
    int t = tid + i*256;             // 0..2047
    int c = t & 127, kg = t >> 7;    // kg: k-group 0..15
    int k0 = kg * 8;
    float w0 = W[(size_t)(k0+0)*128 + c];
    float w1 = W[(size_t)(k0+1)*128 + c];
    float w2 = W[(size_t)(k0+2)*128 + c];
    float w3 = W[(size_t)(k0+3)*128 + c];
    float w4 = W[(size_t)(k0+4)*128 + c];
    float w5 = W[(size_t)(k0+5)*128 + c];
    float w6 = W[(size_t)(k0+6)*128 + c];
    float w7 = W[(size_t)(k0+7)*128 + c];
    uint q0 = (uint)f2bf(w0) | ((uint)f2bf(w1) << 16);
    uint q1 = (uint)f2bf(w2) | ((uint)f2bf(w3) << 16);
    uint q2 = (uint)f2bf(w4) | ((uint)f2bf(w5) << 16);
    uint q3 = (uint)f2bf(w6) | ((uint)f2bf(w7) << 16);
    *(uint4*)&Wt[c*128 + ((kg ^ (c & 7)) << 3)] = make_uint4(q0, q1, q2, q3);
  }
  __syncthreads();

  const int wv   = tid >> 6;
  const int lane = tid & 63;
  const int lr   = lane & 15;          // fragment row/col within 16-tile
  const int lq   = lane >> 4;          // quarter-wave -> k-subgroup
  const int swz  = lr & 7;

  f32x4 acc[2][8];
  #pragma unroll
  for (int m = 0; m < 2; ++m)
    #pragma unroll
    for (int n = 0; n < 8; ++n) acc[m][n] = (f32x4){0.f, 0.f, 0.f, 0.f};

  #pragma unroll
  for (int ks = 0; ks < 4; ++ks){
    int off = ((ks*4 + lq) ^ swz) << 3;          // swizzled k-block byte-offset/2
    short8 a0 = *(const short8*)&Xl[(wv*32 +      lr)*128 + off];
    short8 a1 = *(const short8*)&Xl[(wv*32 + 16 + lr)*128 + off];
    short8 b[8];
    #pragma unroll
    for (int n = 0; n < 8; ++n) b[n] = *(const short8*)&Wt[(n*16 + lr)*128 + off];
    #pragma unroll
    for (int n = 0; n < 8; ++n){
      acc[0][n] = __builtin_amdgcn_mfma_f32_16x16x32_bf16(a0, b[n], acc[0][n], 0, 0, 0);
      acc[1][n] = __builtin_amdgcn_mfma_f32_16x16x32_bf16(a1, b[n], acc[1][n], 0, 0, 0);
    }
  }

  // epilogue: C row = 4*lq + reg, col = lr; apply dinv, cast bf16, store
  #pragma unroll
  for (int m = 0; m < 2; ++m){
    int rbase = r0 + wv*32 + m*16 + 4*lq;
    float dv[4]; bool ok[4];
    #pragma unroll
    for (int rg = 0; rg < 4; ++rg){
      int row = rbase + rg;
      ok[rg] = row < N;
      dv[rg] = dinv[ok[rg] ? row : (N-1)];
    }
    #pragma unroll
    for (int n = 0; n < 8; ++n){
      #pragma unroll
      for (int rg = 0; rg < 4; ++rg){
        if (ok[rg]){
          G[(size_t)(rbase + rg)*128 + n*16 + lr] = f2bf(acc[m][n][rg] * dv[rg]);
        }
      }
    }
  }
}

// ---------------- out[d] = relu(dinv[d]*(g[d] + sum g[src]) + b)  (G bf16, OUT fp32) ----------------
// One wave per node; lane owns cols (2l, 2l+1) = one u32 of 2 bf16 -> 256B coalesced row gathers.

__global__ __launch_bounds__(256) void k_agg(const ushort* __restrict__ G, const int* __restrict__ ofs,
                                             const int* __restrict__ csr, const float* __restrict__ dinv,
                                             const float* __restrict__ bias, float* __restrict__ OUT, int N){
  int wv   = __builtin_amdgcn_readfirstlane((int)(threadIdx.x >> 6));
  int lane = threadIdx.x & 63;
  int d = blockIdx.x*4 + wv;
  if (d >= N) return;
  const uint* Gu = (const uint*)G;    // row stride 64 uints
  float bx = bias[2*lane], by = bias[2*lane+1];
  int e0 = ofs[d], e1 = ofs[d+1];
  uint u0 = Gu[(size_t)d*64 + lane];
  float a0x = bf_lo(u0), a0y = bf_hi(u0);
  float a1x=0.f,a1y=0.f,a2x=0.f,a2y=0.f,a3x=0.f,a3y=0.f;
  int e = e0;
  for (; e+8 <= e1; e += 8){
    int s0=csr[e],   s1=csr[e+1], s2=csr[e+2], s3=csr[e+3];
    int s4=csr[e+4], s5=csr[e+5], s6=csr[e+6], s7=csr[e+7];
    uint v0 = Gu[(size_t)s0*64 + lane];
    uint v1 = Gu[(size_t)s1*64 + lane];
    uint v2 = Gu[(size_t)s2*64 + lane];
    uint v3 = Gu[(size_t)s3*64 + lane];
    uint v4 = Gu[(size_t)s4*64 + lane];
    uint v5 = Gu[(size_t)s5*64 + lane];
    uint v6 = Gu[(size_t)s6*64 + lane];
    uint v7 = Gu[(size_t)s7*64 + lane];
    a0x += bf_lo(v0); a0y += bf_hi(v0);
    a1x += bf_lo(v1); a1y += bf_hi(v1);
    a2x += bf_lo(v2); a2y += bf_hi(v2);
    a3x += bf_lo(v3); a3y += bf_hi(v3);
    a0x += bf_lo(v4); a0y += bf_hi(v4);
    a1x += bf_lo(v5); a1y += bf_hi(v5);
    a2x += bf_lo(v6); a2y += bf_hi(v6);
    a3x += bf_lo(v7); a3y += bf_hi(v7);
  }
  for (; e+4 <= e1; e += 4){
    int s0=csr[e], s1=csr[e+1], s2=csr[e+2], s3=csr[e+3];
    uint v0 = Gu[(size_t)s0*64 + lane];
    uint v1 = Gu[(size_t)s1*64 + lane];
    uint v2 = Gu[(size_t)s2*64 + lane];
    uint v3 = Gu[(size_t)s3*64 + lane];
    a0x += bf_lo(v0); a0y += bf_hi(v0);
    a1x += bf_lo(v1); a1y += bf_hi(v1);
    a2x += bf_lo(v2); a2y += bf_hi(v2);
    a3x += bf_lo(v3); a3y += bf_hi(v3);
  }
  for (; e < e1; ++e){
    int s = csr[e];
    uint v = Gu[(size_t)s*64 + lane];
    a0x += bf_lo(v); a0y += bf_hi(v);
  }
  float sx = (a0x+a1x)+(a2x+a3x), sy = (a0y+a1y)+(a2y+a3y);
  float dv = dinv[d];
  float rx = fmaxf(fmaf(dv, sx, bx), 0.f);
  float ry = fmaxf(fmaf(dv, sy, by), 0.f);
  *(float2*)&OUT[(size_t)d*128 + 2*lane] = make_float2(rx, ry);
}

// ---------------- heads: mean = H@Wm+bm, logstd = H@Ws+bs  (H fp32, out cols = 16+16) ----------------

__global__ __launch_bounds__(256, 2) void k_heads(const float* __restrict__ H, const float* __restrict__ Wm,
                                                  const float* __restrict__ bm, const float* __restrict__ Ws,
                                                  const float* __restrict__ bs, float* __restrict__ OUT, int N){
  __shared__ float Hl[128*66];   // [row][k'] padded stride 66
  __shared__ float Wl[128*32];   // [k][col0-15=Wm,16-31=Ws]
  const int tid = threadIdx.x;
  const int tx = tid & 3;        // col group: 8*tx .. 8*tx+7
  const int ty = tid >> 2;       // rows 2*ty, 2*ty+1
  const int r0 = blockIdx.x * 128;

  for (int i = tid; i < 128*16; i += 256){
    int k = i >> 4, cc = i & 15;
    Wl[k*32 + cc]      = Wm[i];
    Wl[k*32 + 16 + cc] = Ws[i];
  }

  float acc[2][8];
  #pragma unroll
  for (int j=0;j<2;++j)
    #pragma unroll
    for (int c=0;c<8;++c) acc[j][c] = 0.f;

  const float2* H2 = (const float2*)H;
  float2* Hl2 = (float2*)Hl;     // row stride 33 float2
  const float4* Wl4 = (const float4*)Wl;

  for (int kh = 0; kh < 2; ++kh){
    if (kh) __syncthreads();
    #pragma unroll
    for (int i=0;i<16;++i){
      int t = tid + i*256;       // 0..4095
      int r = t >> 5, j = t & 31;
      int rs = r0 + r; if (rs >= N) rs = N - 1;
      Hl2[r*33 + j] = H2[(size_t)rs*64 + kh*32 + j];
    }
    __syncthreads();

    #pragma unroll 4
    for (int k2 = 0; k2 < 32; ++k2){
      float2 x0 = Hl2[(2*ty)*33 + k2];
      float2 x1 = Hl2[(2*ty+1)*33 + k2];
      float4 wa0 = Wl4[(kh*64 + 2*k2)*8   + 2*tx];
      float4 wa1 = Wl4[(kh*64 + 2*k2)*8   + 2*tx + 1];
      float4 wb0 = Wl4[(kh*64 + 2*k2+1)*8 + 2*tx];
      float4 wb1 = Wl4[(kh*64 + 2*k2+1)*8 + 2*tx + 1];
      #pragma unroll
      for (int rr=0;rr<2;++rr){
        float xa = rr ? x1.x : x0.x;
        float xb = rr ? x1.y : x0.y;
        acc[rr][0] = fmaf(xa, wa0.x, acc[rr][0]);
        acc[rr][1] = fmaf(xa, wa0.y, acc[rr][1]);
        acc[rr][2] = fmaf(xa, wa0.z, acc[rr][2]);
        acc[rr][3] = fmaf(xa, wa0.w, acc[rr][3]);
        acc[rr][4] = fmaf(xa, wa1.x, acc[rr][4]);
        acc[rr][5] = fmaf(xa, wa1.y, acc[rr][5]);
        acc[rr][6] = fmaf(xa, wa1.z, acc[rr][6]);
        acc[rr][7] = fmaf(xa, wa1.w, acc[rr][7]);
        acc[rr][0] = fmaf(xb, wb0.x, acc[rr][0]);
        acc[rr][1] = fmaf(xb, wb0.y, acc[rr][1]);
        acc[rr][2] = fmaf(xb, wb0.z, acc[rr][2]);
        acc[rr][3] = fmaf(xb, wb0.w, acc[rr][3]);
        acc[rr][4] = fmaf(xb, wb1.x, acc[rr][4]);
        acc[rr][5] = fmaf(xb, wb1.y, acc[rr][5]);
        acc[rr][6] = fmaf(xb, wb1.z, acc[rr][6]);
        acc[rr][7] = fmaf(xb, wb1.w, acc[rr][7]);
      }
    }
  }

  int c0 = 8*tx;
  float bv[8];
  #pragma unroll
  for (int i=0;i<8;++i) bv[i] = (tx < 2) ? bm[c0+i] : bs[c0+i-16];
  #pragma unroll
  for (int rr=0;rr<2;++rr){
    int row = r0 + 2*ty + rr;
    if (row < N){
      float4 o0 = make_float4(acc[rr][0]+bv[0], acc[rr][1]+bv[1], acc[rr][2]+bv[2], acc[rr][3]+bv[3]);
      float4 o1 = make_float4(acc[rr][4]+bv[4], acc[rr][5]+bv[5], acc[rr][6]+bv[6], acc[rr][7]+bv[7]);
      float* base = (tx < 2) ? &OUT[(size_t)row*16 + c0]
                             : &OUT[(size_t)N*16 + (size_t)row*16 + (c0-16)];
      float4* Op = (float4*)base;
      Op[0] = o0; Op[1] = o1;
    }
  }
}

// ---------------- host ----------------

extern "C" void kernel_launch(void* const* d_in, const int* in_sizes, int n_in,
                              void* d_out, int out_size, void* d_ws, size_t ws_size,
                              hipStream_t stream){
  const float* x  = (const float*)d_in[0];
  const int*   ei = (const int*)d_in[1];
  const float* W1 = (const float*)d_in[2];
  const float* b1 = (const float*)d_in[3];
  const float* W2 = (const float*)d_in[4];
  const float* b2 = (const float*)d_in[5];
  const float* Wm = (const float*)d_in[6];
  const float* bm = (const float*)d_in[7];
  const float* Ws = (const float*)d_in[8];
  const float* bs = (const float*)d_in[9];
  float* out = (float*)d_out;

  int N = in_sizes[0] / 128;
  int E = in_sizes[1] / 2;
  const int* src = ei;
  const int* dst = ei + E;

  char* w = (char*)d_ws;
  size_t o = 0;
  auto alloc = [&](size_t bytes)->char*{
    char* p = w + o; o = (o + bytes + 255) & ~(size_t)255; return p;
  };
  int*    bcnt = (int*)   alloc(1024*4);
  int*    boff = (int*)   alloc(1025*4);
  int*    bcur = (int*)   alloc(1024*4);
  float*  dinv = (float*) alloc((size_t)N*4);
  int*    ofs  = (int*)   alloc((size_t)(N+1)*4);
  uint*   ebuf = (uint*)  alloc((size_t)E*4);
  int*    csr  = (int*)   alloc((size_t)E*4);
  ushort* bufG = (ushort*)alloc((size_t)N*128*2);   // bf16 G (both layers)
  float*  bufH = (float*) alloc((size_t)N*128*4);   // fp32 h (both layers)
  (void)ws_size; (void)n_in; (void)out_size;

  hipMemsetAsync(bcnt, 0, 1024*4, stream);

  int NB = (N + 127)/128;                     // 782 buckets for N=100000
  int CH = (E + 255)/256; CH = (CH + 3) & ~3; // chunk per wg for 256-wg passes

  k_bcount  <<<256, 256, 0, stream>>>(dst, E, CH, bcnt);
  k_bscan   <<<1,   256, 0, stream>>>(bcnt, boff, bcur, E);
  k_bscatter<<<256, 256, 0, stream>>>(src, dst, E, CH, bcur, ebuf);
  k_csr     <<<NB,  256, 0, stream>>>(ebuf, boff, dinv, ofs, csr, N);
  if ((N & 127) == 0) k_ofs_last<<<1, 1, 0, stream>>>(ofs, N, E);  // only when N%128==0 (not hit for 100000)

  int gAgg = (N + 3)/4;

  k_gemm_mfma<<<NB,   256, 0, stream>>>(x,    W1, dinv, bufG, N);             // g1 (bf16, MFMA)
  k_agg      <<<gAgg, 256, 0, stream>>>(bufG, ofs, csr, dinv, b1, bufH, N);   // h1 = relu(...) fp32
  k_gemm_mfma<<<NB,   256, 0, stream>>>(bufH, W2, dinv, bufG, N);             // g2 (bf16, MFMA)
  k_agg      <<<gAgg, 256, 0, stream>>>(bufG, ofs, csr, dinv, b2, bufH, N);   // h2 fp32
  k_heads    <<<NB,   256, 0, stream>>>(bufH, Wm, bm, Ws, bs, out, N);
}

// Round 13
// 326.862 us; speedup vs baseline: 9.1125x; 1.0277x over previous
//
#include <hip/hip_runtime.h>
#include <hip/hip_bf16.h>
#include <stdint.h>

static __device__ __forceinline__ ushort f2bf(float f){
  uint u = __float_as_uint(f);
  uint r = (u + 0x7fffu + ((u >> 16) & 1u)) >> 16;   // round-to-nearest-even
  return (ushort)r;
}
static __device__ __forceinline__ float bf_lo(uint v){ return __uint_as_float(v << 16); }
static __device__ __forceinline__ float bf_hi(uint v){ return __uint_as_float(v & 0xffff0000u); }

using short8 = __attribute__((ext_vector_type(8))) short;
using f32x4  = __attribute__((ext_vector_type(4))) float;

// Buckets: 128 nodes per bucket (bucket = dst >> 7). NB <= 1024 (N <= 131072).
// Edge pack: e = src | (dst&127)<<20  (requires N < 2^20; here N = 100000).

// ---------------- bucket count (LDS-aggregated histogram) ----------------

__global__ __launch_bounds__(256) void k_bcount(const int* __restrict__ dst, int E, int CH,
                                                int* __restrict__ bcnt){
  __shared__ int hist[1024];
  for (int i = threadIdx.x; i < 1024; i += 256) hist[i] = 0;
  __syncthreads();
  int begin = blockIdx.x * CH;
  int end   = min(begin + CH, E);
  int i0 = begin + threadIdx.x * 4;
  for (int i = i0; i + 4 <= end; i += 1024){
    int4 d4 = *(const int4*)&dst[i];
    atomicAdd(&hist[d4.x >> 7], 1);
    atomicAdd(&hist[d4.y >> 7], 1);
    atomicAdd(&hist[d4.z >> 7], 1);
    atomicAdd(&hist[d4.w >> 7], 1);
  }
  int tailStart = begin + ((end - begin) & ~3);
  if (tailStart < end && threadIdx.x < (end - tailStart)){
    atomicAdd(&hist[dst[tailStart + threadIdx.x] >> 7], 1);
  }
  __syncthreads();
  for (int b = threadIdx.x; b < 1024; b += 256){
    int h = hist[b];
    if (h) atomicAdd(&bcnt[b], h);
  }
}

// ---------------- bucket scan (1 wg, 1024 entries) ----------------

__global__ __launch_bounds__(256) void k_bscan(const int* __restrict__ bcnt, int* __restrict__ boff,
                                               int* __restrict__ bcur, int E){
  __shared__ int sh[256];
  int t = threadIdx.x, base = t * 4;
  int v0 = bcnt[base], v1 = bcnt[base+1], v2 = bcnt[base+2], v3 = bcnt[base+3];
  int s = v0 + v1 + v2 + v3;
  sh[t] = s; __syncthreads();
  for (int off = 1; off < 256; off <<= 1){
    int x = (t >= off) ? sh[t-off] : 0;
    __syncthreads(); sh[t] += x; __syncthreads();
  }
  int run = sh[t] - s;
  boff[base]   = run; bcur[base]   = run; run += v0;
  boff[base+1] = run; bcur[base+1] = run; run += v1;
  boff[base+2] = run; bcur[base+2] = run; run += v2;
  boff[base+3] = run; bcur[base+3] = run; run += v3;
  if (t == 255) boff[1024] = E;
}

// ---------------- bucket scatter (packed uint edges, LDS block reservation) ----------------

__global__ __launch_bounds__(256) void k_bscatter(const int* __restrict__ src, const int* __restrict__ dst,
                                                  int E, int CH, int* __restrict__ bcur,
                                                  uint* __restrict__ ebuf){
  __shared__ int hist[1024];
  __shared__ int basea[1024];
  __shared__ int cnt[1024];
  for (int i = threadIdx.x; i < 1024; i += 256){ hist[i] = 0; cnt[i] = 0; }
  __syncthreads();
  int begin = blockIdx.x * CH;
  int end   = min(begin + CH, E);
  int i0 = begin + threadIdx.x * 4;
  for (int i = i0; i + 4 <= end; i += 1024){
    int4 d4 = *(const int4*)&dst[i];
    atomicAdd(&hist[d4.x >> 7], 1);
    atomicAdd(&hist[d4.y >> 7], 1);
    atomicAdd(&hist[d4.z >> 7], 1);
    atomicAdd(&hist[d4.w >> 7], 1);
  }
  int tailStart = begin + ((end - begin) & ~3);
  if (tailStart < end && threadIdx.x < (end - tailStart)){
    atomicAdd(&hist[dst[tailStart + threadIdx.x] >> 7], 1);
  }
  __syncthreads();
  for (int b = threadIdx.x; b < 1024; b += 256){
    int h = hist[b];
    basea[b] = h ? atomicAdd(&bcur[b], h) : 0;     // reserve contiguous block per bucket
  }
  __syncthreads();
  for (int i = i0; i + 4 <= end; i += 1024){
    int4 d4 = *(const int4*)&dst[i];
    int4 s4 = *(const int4*)&src[i];
    int b0 = d4.x >> 7; int p0 = basea[b0] + atomicAdd(&cnt[b0], 1);
    ebuf[p0] = (uint)s4.x | (((uint)d4.x & 127u) << 20);
    int b1 = d4.y >> 7; int p1 = basea[b1] + atomicAdd(&cnt[b1], 1);
    ebuf[p1] = (uint)s4.y | (((uint)d4.y & 127u) << 20);
    int b2 = d4.z >> 7; int p2 = basea[b2] + atomicAdd(&cnt[b2], 1);
    ebuf[p2] = (uint)s4.z | (((uint)d4.z & 127u) << 20);
    int b3 = d4.w >> 7; int p3 = basea[b3] + atomicAdd(&cnt[b3], 1);
    ebuf[p3] = (uint)s4.w | (((uint)d4.w & 127u) << 20);
  }
  if (tailStart < end && threadIdx.x < (end - tailStart)){
    int j = tailStart + threadIdx.x;
    int d = dst[j], s = src[j];
    int b = d >> 7; int p = basea[b] + atomicAdd(&cnt[b], 1);
    ebuf[p] = (uint)s | (((uint)d & 127u) << 20);
  }
}

// ---------------- per-bucket CSR finalize: degree->dinv, node scan->ofs, scatter src->csr ----------------

__global__ __launch_bounds__(256) void k_csr(const uint* __restrict__ ebuf, const int* __restrict__ boff,
                                             float* __restrict__ dinv, int* __restrict__ ofs,
                                             int* __restrict__ csr, int N){
  __shared__ int cnt[128];
  __shared__ int esc[128];
  __shared__ int cur[128];
  const int b = blockIdx.x;
  const int t = threadIdx.x;
  if (t < 128) cnt[t] = 0;
  __syncthreads();
  const int e0 = boff[b], e1 = boff[b+1];
  for (int i = e0 + t; i < e1; i += 256){
    atomicAdd(&cnt[(ebuf[i] >> 20) & 127u], 1);
  }
  __syncthreads();
  if (t < 128) esc[t] = cnt[t];
  __syncthreads();
  for (int off = 1; off < 128; off <<= 1){
    int v = 0;
    if (t < 128 && t >= off) v = esc[t - off];
    __syncthreads();
    if (t < 128) esc[t] += v;
    __syncthreads();
  }
  if (t < 128){
    int ex = esc[t] - cnt[t];              // exclusive scan
    cur[t] = ex;
    int node = b*128 + t;
    if (node < N){
      dinv[node] = rsqrtf((float)(cnt[t] + 1));
      ofs[node]  = e0 + ex;
    } else if (node == N){
      ofs[N] = e0 + ex;                    // == e1 == E when N falls inside this bucket
    }
  }
  __syncthreads();
  for (int i = e0 + t; i < e1; i += 256){
    uint e = ebuf[i];
    int loc = (int)((e >> 20) & 127u);
    int p = e0 + atomicAdd(&cur[loc], 1);
    csr[p] = (int)(e & 0xFFFFFu);
  }
}

__global__ void k_ofs_last(int* __restrict__ ofs, int N, int E){ ofs[N] = E; }

// ---------------- g = bf16((X @ W) * dinv[row])  via MFMA bf16 (X fp32 -> bf16 staged) ----------------
// Tile 128x128, whole K=128 in LDS (Xl + Wt = 64 KB). XOR-swizzled layout:
//   elem (r, k) at r*128 + 8*((k/8) ^ (r&7)) + (k&7)   -> all frag reads / staged writes bank-conflict-free.
// 4 waves; wave w owns rows 32w..32w+31 (2 tiles of 16) x 8 col tiles; 64 MFMAs/wave.

__global__ __launch_bounds__(256, 2) void k_gemm_mfma(const float* __restrict__ X, const float* __restrict__ W,
                                                      const float* __restrict__ dinv, ushort* __restrict__ G, int N){
  __shared__ ushort Xl[128*128];   // 32 KB  [row][k] swizzled
  __shared__ ushort Wt[128*128];   // 32 KB  [col][k] swizzled (W transposed)
  const int tid = threadIdx.x;
  const int r0 = blockIdx.x * 128;

  #pragma unroll
  for (int i = 0; i < 16; ++i){
    int t = tid + i*256;             // 0..4095
    int row = t >> 5, f4 = t & 31;
    int rs = r0 + row; if (rs >= N) rs = N - 1;
    float4 v = *(const float4*)&X[(size_t)rs*128 + f4*4];
    uint p0 = (uint)f2bf(v.x) | ((uint)f2bf(v.y) << 16);
    uint p1 = (uint)f2bf(v.z) | ((uint)f2bf(v.w) << 16);
    int kb = f4 >> 1, sub = (f4 & 1) * 4;
    *(uint2*)&Xl[row*128 + ((kb ^ (row & 7)) << 3) + sub] = make_uint2(p0, p1);
  }
  #pragma unroll
  for (int i = 0; i < 8; ++i){
    int t = tid + i*256;             // 0..2047
    int c = t & 127, kg = t >> 7;    // kg: k-group 0..15
    int k0 = kg * 8;
    float w0 = W[(size_t)(k0+0)*128 + c];
    float w1 = W[(size_t)(k0+1)*128 + c];
    float w2 = W[(size_t)(k0+2)*128 + c];
    float w3 = W[(size_t)(k0+3)*128 + c];
    float w4 = W[(size_t)(k0+4)*128 + c];
    float w5 = W[(size_t)(k0+5)*128 + c];
    float w6 = W[(size_t)(k0+6)*128 + c];
    float w7 = W[(size_t)(k0+7)*128 + c];
    uint q0 = (uint)f2bf(w0) | ((uint)f2bf(w1) << 16);
    uint q1 = (uint)f2bf(w2) | ((uint)f2bf(w3) << 16);
    uint q2 = (uint)f2bf(w4) | ((uint)f2bf(w5) << 16);
    uint q3 = (uint)f2bf(w6) | ((uint)f2bf(w7) << 16);
    *(uint4*)&Wt[c*128 + ((kg ^ (c & 7)) << 3)] = make_uint4(q0, q1, q2, q3);
  }
  __syncthreads();

  const int wv   = tid >> 6;
  const int lane = tid & 63;
  const int lr   = lane & 15;
  const int lq   = lane >> 4;
  const int swz  = lr & 7;

  f32x4 acc[2][8];
  #pragma unroll
  for (int m = 0; m < 2; ++m)
    #pragma unroll
    for (int n = 0; n < 8; ++n) acc[m][n] = (f32x4){0.f, 0.f, 0.f, 0.f};

  #pragma unroll
  for (int ks = 0; ks < 4; ++ks){
    int off = ((ks*4 + lq) ^ swz) << 3;
    short8 a0 = *(const short8*)&Xl[(wv*32 +      lr)*128 + off];
    short8 a1 = *(const short8*)&Xl[(wv*32 + 16 + lr)*128 + off];
    short8 b[8];
    #pragma unroll
    for (int n = 0; n < 8; ++n) b[n] = *(const short8*)&Wt[(n*16 + lr)*128 + off];
    #pragma unroll
    for (int n = 0; n < 8; ++n){
      acc[0][n] = __builtin_amdgcn_mfma_f32_16x16x32_bf16(a0, b[n], acc[0][n], 0, 0, 0);
      acc[1][n] = __builtin_amdgcn_mfma_f32_16x16x32_bf16(a1, b[n], acc[1][n], 0, 0, 0);
    }
  }

  #pragma unroll
  for (int m = 0; m < 2; ++m){
    int rbase = r0 + wv*32 + m*16 + 4*lq;
    float dv[4]; bool ok[4];
    #pragma unroll
    for (int rg = 0; rg < 4; ++rg){
      int row = rbase + rg;
      ok[rg] = row < N;
      dv[rg] = dinv[ok[rg] ? row : (N-1)];
    }
    #pragma unroll
    for (int n = 0; n < 8; ++n){
      #pragma unroll
      for (int rg = 0; rg < 4; ++rg){
        if (ok[rg]){
          G[(size_t)(rbase + rg)*128 + n*16 + lr] = f2bf(acc[m][n][rg] * dv[rg]);
        }
      }
    }
  }
}

// ---------------- out[d] = relu(dinv[d]*(g[d] + sum g[src]) + b)  (G bf16, OUT fp32) ----------------
// One wave per node; lane owns cols (2l, 2l+1) = one u32 of 2 bf16 -> 256B coalesced row gathers.

__global__ __launch_bounds__(256) void k_agg(const ushort* __restrict__ G, const int* __restrict__ ofs,
                                             const int* __restrict__ csr, const float* __restrict__ dinv,
                                             const float* __restrict__ bias, float* __restrict__ OUT, int N){
  int wv   = __builtin_amdgcn_readfirstlane((int)(threadIdx.x >> 6));
  int lane = threadIdx.x & 63;
  int d = blockIdx.x*4 + wv;
  if (d >= N) return;
  const uint* Gu = (const uint*)G;    // row stride 64 uints
  float bx = bias[2*lane], by = bias[2*lane+1];
  int e0 = ofs[d], e1 = ofs[d+1];
  uint u0 = Gu[(size_t)d*64 + lane];
  float a0x = bf_lo(u0), a0y = bf_hi(u0);
  float a1x=0.f,a1y=0.f,a2x=0.f,a2y=0.f,a3x=0.f,a3y=0.f;
  int e = e0;
  for (; e+8 <= e1; e += 8){
    int s0=csr[e],   s1=csr[e+1], s2=csr[e+2], s3=csr[e+3];
    int s4=csr[e+4], s5=csr[e+5], s6=csr[e+6], s7=csr[e+7];
    uint v0 = Gu[(size_t)s0*64 + lane];
    uint v1 = Gu[(size_t)s1*64 + lane];
    uint v2 = Gu[(size_t)s2*64 + lane];
    uint v3 = Gu[(size_t)s3*64 + lane];
    uint v4 = Gu[(size_t)s4*64 + lane];
    uint v5 = Gu[(size_t)s5*64 + lane];
    uint v6 = Gu[(size_t)s6*64 + lane];
    uint v7 = Gu[(size_t)s7*64 + lane];
    a0x += bf_lo(v0); a0y += bf_hi(v0);
    a1x += bf_lo(v1); a1y += bf_hi(v1);
    a2x += bf_lo(v2); a2y += bf_hi(v2);
    a3x += bf_lo(v3); a3y += bf_hi(v3);
    a0x += bf_lo(v4); a0y += bf_hi(v4);
    a1x += bf_lo(v5); a1y += bf_hi(v5);
    a2x += bf_lo(v6); a2y += bf_hi(v6);
    a3x += bf_lo(v7); a3y += bf_hi(v7);
  }
  for (; e+4 <= e1; e += 4){
    int s0=csr[e], s1=csr[e+1], s2=csr[e+2], s3=csr[e+3];
    uint v0 = Gu[(size_t)s0*64 + lane];
    uint v1 = Gu[(size_t)s1*64 + lane];
    uint v2 = Gu[(size_t)s2*64 + lane];
    uint v3 = Gu[(size_t)s3*64 + lane];
    a0x += bf_lo(v0); a0y += bf_hi(v0);
    a1x += bf_lo(v1); a1y += bf_hi(v1);
    a2x += bf_lo(v2); a2y += bf_hi(v2);
    a3x += bf_lo(v3); a3y += bf_hi(v3);
  }
  for (; e < e1; ++e){
    int s = csr[e];
    uint v = Gu[(size_t)s*64 + lane];
    a0x += bf_lo(v); a0y += bf_hi(v);
  }
  float sx = (a0x+a1x)+(a2x+a3x), sy = (a0y+a1y)+(a2y+a3y);
  float dv = dinv[d];
  float rx = fmaxf(fmaf(dv, sx, bx), 0.f);
  float ry = fmaxf(fmaf(dv, sy, by), 0.f);
  *(float2*)&OUT[(size_t)d*128 + 2*lane] = make_float2(rx, ry);
}

// ---------------- heads via MFMA: mean = H@Wm+bm, logstd = H@Ws+bs ----------------
// Same structure as k_gemm_mfma; 32 output cols (0-15 mean, 16-31 logstd). LDS 40 KB.
// 4 waves x 2 m-tiles x 2 col-tiles = 16 MFMAs/wave; fp32 epilogue + bias.

__global__ __launch_bounds__(256, 2) void k_heads_mfma(const float* __restrict__ H, const float* __restrict__ Wm,
                                                       const float* __restrict__ bm, const float* __restrict__ Ws,
                                                       const float* __restrict__ bs, float* __restrict__ OUT, int N){
  __shared__ ushort Xl[128*128];   // 32 KB [row][k] swizzled
  __shared__ ushort Wt[32*128];    //  8 KB [col][k] swizzled; col<16 = Wm, col>=16 = Ws
  const int tid = threadIdx.x;
  const int r0 = blockIdx.x * 128;

  #pragma unroll
  for (int i = 0; i < 16; ++i){
    int t = tid + i*256;
    int row = t >> 5, f4 = t & 31;
    int rs = r0 + row; if (rs >= N) rs = N - 1;
    float4 v = *(const float4*)&H[(size_t)rs*128 + f4*4];
    uint p0 = (uint)f2bf(v.x) | ((uint)f2bf(v.y) << 16);
    uint p1 = (uint)f2bf(v.z) | ((uint)f2bf(v.w) << 16);
    int kb = f4 >> 1, sub = (f4 & 1) * 4;
    *(uint2*)&Xl[row*128 + ((kb ^ (row & 7)) << 3) + sub] = make_uint2(p0, p1);
  }
  // stage Wm|Ws transposed + swizzled: 512 items (c 0..31, kg 0..15)
  #pragma unroll
  for (int i = 0; i < 2; ++i){
    int t = tid + i*256;             // 0..511
    int c = t & 31, kg = t >> 5;
    const float* Wp = (c < 16) ? (Wm + c) : (Ws + (c - 16));
    int k0 = kg * 8;
    uint q0 = (uint)f2bf(Wp[(size_t)(k0+0)*16]) | ((uint)f2bf(Wp[(size_t)(k0+1)*16]) << 16);
    uint q1 = (uint)f2bf(Wp[(size_t)(k0+2)*16]) | ((uint)f2bf(Wp[(size_t)(k0+3)*16]) << 16);
    uint q2 = (uint)f2bf(Wp[(size_t)(k0+4)*16]) | ((uint)f2bf(Wp[(size_t)(k0+5)*16]) << 16);
    uint q3 = (uint)f2bf(Wp[(size_t)(k0+6)*16]) | ((uint)f2bf(Wp[(size_t)(k0+7)*16]) << 16);
    *(uint4*)&Wt[c*128 + ((kg ^ (c & 7)) << 3)] = make_uint4(q0, q1, q2, q3);
  }
  __syncthreads();

  const int wv   = tid >> 6;
  const int lane = tid & 63;
  const int lr   = lane & 15;
  const int lq   = lane >> 4;
  const int swz  = lr & 7;

  f32x4 acc[2][2];
  #pragma unroll
  for (int m = 0; m < 2; ++m)
    #pragma unroll
    for (int n = 0; n < 2; ++n) acc[m][n] = (f32x4){0.f, 0.f, 0.f, 0.f};

  #pragma unroll
  for (int ks = 0; ks < 4; ++ks){
    int off = ((ks*4 + lq) ^ swz) << 3;
    short8 a0 = *(const short8*)&Xl[(wv*32 +      lr)*128 + off];
    short8 a1 = *(const short8*)&Xl[(wv*32 + 16 + lr)*128 + off];
    short8 b0 = *(const short8*)&Wt[(     lr)*128 + off];
    short8 b1 = *(const short8*)&Wt[(16 + lr)*128 + off];
    acc[0][0] = __builtin_amdgcn_mfma_f32_16x16x32_bf16(a0, b0, acc[0][0], 0, 0, 0);
    acc[0][1] = __builtin_amdgcn_mfma_f32_16x16x32_bf16(a0, b1, acc[0][1], 0, 0, 0);
    acc[1][0] = __builtin_amdgcn_mfma_f32_16x16x32_bf16(a1, b0, acc[1][0], 0, 0, 0);
    acc[1][1] = __builtin_amdgcn_mfma_f32_16x16x32_bf16(a1, b1, acc[1][1], 0, 0, 0);
  }

  // C/D: row = 4*lq + reg (within 16-tile), col = lr. mean col=lr, logstd col=lr.
  float bv0 = bm[lr], bv1 = bs[lr];
  #pragma unroll
  for (int m = 0; m < 2; ++m){
    int rbase = r0 + wv*32 + m*16 + 4*lq;
    #pragma unroll
    for (int rg = 0; rg < 4; ++rg){
      int row = rbase + rg;
      if (row < N){
        OUT[(size_t)row*16 + lr]                    = acc[m][0][rg] + bv0;
        OUT[(size_t)N*16 + (size_t)row*16 + lr]     = acc[m][1][rg] + bv1;
      }
    }
  }
}

// ---------------- host ----------------

extern "C" void kernel_launch(void* const* d_in, const int* in_sizes, int n_in,
                              void* d_out, int out_size, void* d_ws, size_t ws_size,
                              hipStream_t stream){
  const float* x  = (const float*)d_in[0];
  const int*   ei = (const int*)d_in[1];
  const float* W1 = (const float*)d_in[2];
  const float* b1 = (const float*)d_in[3];
  const float* W2 = (const float*)d_in[4];
  const float* b2 = (const float*)d_in[5];
  const float* Wm = (const float*)d_in[6];
  const float* bm = (const float*)d_in[7];
  const float* Ws = (const float*)d_in[8];
  const float* bs = (const float*)d_in[9];
  float* out = (float*)d_out;

  int N = in_sizes[0] / 128;
  int E = in_sizes[1] / 2;
  const int* src = ei;
  const int* dst = ei + E;

  char* w = (char*)d_ws;
  size_t o = 0;
  auto alloc = [&](size_t bytes)->char*{
    char* p = w + o; o = (o + bytes + 255) & ~(size_t)255; return p;
  };
  int*    bcnt = (int*)   alloc(1024*4);
  int*    boff = (int*)   alloc(1025*4);
  int*    bcur = (int*)   alloc(1024*4);
  float*  dinv = (float*) alloc((size_t)N*4);
  int*    ofs  = (int*)   alloc((size_t)(N+1)*4);
  uint*   ebuf = (uint*)  alloc((size_t)E*4);
  int*    csr  = (int*)   alloc((size_t)E*4);
  ushort* bufG = (ushort*)alloc((size_t)N*128*2);   // bf16 G (both layers)
  float*  bufH = (float*) alloc((size_t)N*128*4);   // fp32 h (both layers)
  (void)ws_size; (void)n_in; (void)out_size;

  hipMemsetAsync(bcnt, 0, 1024*4, stream);

  int NB = (N + 127)/128;                     // 782 buckets for N=100000
  int CH = (E + 255)/256; CH = (CH + 3) & ~3; // chunk per wg for 256-wg passes

  k_bcount  <<<256, 256, 0, stream>>>(dst, E, CH, bcnt);
  k_bscan   <<<1,   256, 0, stream>>>(bcnt, boff, bcur, E);
  k_bscatter<<<256, 256, 0, stream>>>(src, dst, E, CH, bcur, ebuf);
  k_csr     <<<NB,  256, 0, stream>>>(ebuf, boff, dinv, ofs, csr, N);
  if ((N & 127) == 0) k_ofs_last<<<1, 1, 0, stream>>>(ofs, N, E);  // only when N%128==0 (not hit for 100000)

  int gAgg = (N + 3)/4;

  k_gemm_mfma <<<NB,   256, 0, stream>>>(x,    W1, dinv, bufG, N);             // g1 (bf16, MFMA)
  k_agg       <<<gAgg, 256, 0, stream>>>(bufG, ofs, csr, dinv, b1, bufH, N);   // h1 = relu(...) fp32
  k_gemm_mfma <<<NB,   256, 0, stream>>>(bufH, W2, dinv, bufG, N);             // g2 (bf16, MFMA)
  k_agg       <<<gAgg, 256, 0, stream>>>(bufG, ofs, csr, dinv, b2, bufH, N);   // h2 fp32
  k_heads_mfma<<<NB,   256, 0, stream>>>(bufH, Wm, bm, Ws, bs, out, N);
}